// Round 3
// baseline (1417.437 us; speedup 1.0000x reference)
//
#include <hip/hip_runtime.h>
#include <cstdint>
#include <cstddef>

#define S_LEN 4096
#define HID   3584
#define NH    16
#define NKV   8
#define HD    256
#define QSZ   (NH*HD)            // 4096
#define KVSZ  (NKV*HD)           // 2048
#define QKV_N (QSZ + 2*KVSZ)     // 8192
#define WINDOW 2047

typedef unsigned short u16;
typedef __bf16 bf16x8 __attribute__((ext_vector_type(8)));
typedef u16    u16x8  __attribute__((ext_vector_type(8)));
typedef u16    u16x4  __attribute__((ext_vector_type(4)));
typedef float  f32x4  __attribute__((ext_vector_type(4)));

__device__ inline float bf2f(u16 u) {
    union { unsigned u; float f; } v; v.u = ((unsigned)u) << 16; return v.f;
}
__device__ inline u16 f2bf(float f) {
    union { float f; unsigned u; } v; v.f = f;
    return (u16)((v.u + 0x7FFF + ((v.u >> 16) & 1)) >> 16);
}

// async global->LDS DMA, 16B per lane; LDS dest = wave-uniform base + lane*16
__device__ inline void gl_lds16(const void* g, void* l) {
    __builtin_amdgcn_global_load_lds(
        (const __attribute__((address_space(1))) void*)g,
        (__attribute__((address_space(3))) void*)l,
        16, 0, 0);
}

// ---------------- fp32 -> bf16 cast (vectorized) ----------------
__global__ __launch_bounds__(256)
void cast_f32_bf16(const float* __restrict__ src, u16* __restrict__ dst, int n4) {
    int i = blockIdx.x * blockDim.x + threadIdx.x;
    if (i >= n4) return;
    float4 v = ((const float4*)src)[i];
    u16x4 o;
    o[0] = f2bf(v.x); o[1] = f2bf(v.y); o[2] = f2bf(v.z); o[3] = f2bf(v.w);
    ((u16x4*)dst)[i] = o;
}

// ---------------- bf16 GEMM, C[m,n] = sum_k A[m,k]*B[n,k] (both K-major) ----
// 128x128 tile, BK=32, 4 waves 2x2, global_load_lds width-16 staging (m97).
template<int BF16OUT>
__global__ __launch_bounds__(256)
void gemm_bt(const u16* __restrict__ A, const u16* __restrict__ B,
             void* __restrict__ Cv, int M, int N, int K) {
    __shared__ u16 lA[128 * 32];
    __shared__ u16 lB[128 * 32];
    const int tid  = threadIdx.x;
    const int lane = tid & 63, wave = tid >> 6;
    const int quad = lane >> 4, l16 = lane & 15;
    const int m0 = blockIdx.y * 128, n0 = blockIdx.x * 128;
    const int wm = (wave & 1) * 64, wn = (wave >> 1) * 64;

    const int c0 = wave * 128 + lane, c1 = c0 + 64;
    const u16* gA0 = A + (size_t)(m0 + (c0 >> 2)) * K + (c0 & 3) * 8;
    const u16* gA1 = A + (size_t)(m0 + (c1 >> 2)) * K + (c1 & 3) * 8;
    const u16* gB0 = B + (size_t)(n0 + (c0 >> 2)) * K + (c0 & 3) * 8;
    const u16* gB1 = B + (size_t)(n0 + (c1 >> 2)) * K + (c1 & 3) * 8;
    char* lA0 = (char*)lA + wave * 2048;
    char* lB0 = (char*)lB + wave * 2048;

    f32x4 zero = {0.f, 0.f, 0.f, 0.f};
    f32x4 acc[4][4];
#pragma unroll
    for (int i = 0; i < 4; ++i)
#pragma unroll
        for (int j = 0; j < 4; ++j) acc[i][j] = zero;

    for (int k0 = 0; k0 < K; k0 += 32) {
        __syncthreads();
        gl_lds16(gA0 + k0, lA0);
        gl_lds16(gA1 + k0, lA0 + 1024);
        gl_lds16(gB0 + k0, lB0);
        gl_lds16(gB1 + k0, lB0 + 1024);
        __syncthreads();

        bf16x8 af[4], bfr[4];
#pragma unroll
        for (int mt = 0; mt < 4; ++mt)
            af[mt] = *(const bf16x8*)(&lA[(wm + mt * 16 + l16) * 32 + quad * 8]);
#pragma unroll
        for (int nt = 0; nt < 4; ++nt)
            bfr[nt] = *(const bf16x8*)(&lB[(wn + nt * 16 + l16) * 32 + quad * 8]);
#pragma unroll
        for (int mt = 0; mt < 4; ++mt)
#pragma unroll
            for (int nt = 0; nt < 4; ++nt)
                acc[mt][nt] = __builtin_amdgcn_mfma_f32_16x16x32_bf16(
                    af[mt], bfr[nt], acc[mt][nt], 0, 0, 0);
    }

#pragma unroll
    for (int mt = 0; mt < 4; ++mt)
#pragma unroll
        for (int nt = 0; nt < 4; ++nt)
#pragma unroll
            for (int r = 0; r < 4; ++r) {
                int row = m0 + wm + mt * 16 + quad * 4 + r;
                int col = n0 + wn + nt * 16 + l16;
                float v = acc[mt][nt][r];
                if (BF16OUT) ((u16*)Cv)[(size_t)row * N + col] = f2bf(v);
                else         ((float*)Cv)[(size_t)row * N + col] = v;
            }
}

// ---------------- RoPE (NeoX) + split + per-head relayout -------------------
__global__ __launch_bounds__(256)
void rope_split(const u16* __restrict__ qkv, u16* __restrict__ Qb,
                u16* __restrict__ Kb, u16* __restrict__ Vb) {
    const int s = blockIdx.x;
    const int t = threadIdx.x;
    const float pos = (float)s;
    const u16* row = qkv + (size_t)s * QKV_N;

    for (int p = t; p < 2048; p += 256) {      // Q: 16 heads x 128 pairs
        int h = p >> 7, d = p & 127;
        float inv = __expf(-(float)d * 0.0719557841560639f);  // ln(1e4)/128
        float ang = pos * inv, sn, cs;
        sincosf(ang, &sn, &cs);
        float x1 = bf2f(row[h * HD + d]);
        float x2 = bf2f(row[h * HD + d + 128]);
        size_t base = ((size_t)h * S_LEN + s) * HD;
        Qb[base + d]       = f2bf((x1 * cs - x2 * sn) * 0.0625f);  // fold 1/16 scale
        Qb[base + d + 128] = f2bf((x2 * cs + x1 * sn) * 0.0625f);
    }
    for (int p = t; p < 1024; p += 256) {      // K: 8 heads x 128 pairs
        int h = p >> 7, d = p & 127;
        float inv = __expf(-(float)d * 0.0719557841560639f);
        float ang = pos * inv, sn, cs;
        sincosf(ang, &sn, &cs);
        float x1 = bf2f(row[QSZ + h * HD + d]);
        float x2 = bf2f(row[QSZ + h * HD + d + 128]);
        size_t base = ((size_t)h * S_LEN + s) * HD;
        Kb[base + d]       = f2bf(x1 * cs - x2 * sn);
        Kb[base + d + 128] = f2bf(x2 * cs + x1 * sn);
    }
    for (int e = t; e < 2048; e += 256) {      // V: natural [h][s][d]
        int h = e >> 8, d = e & 255;
        Vb[((size_t)h * S_LEN + s) * HD + d] = row[QSZ + KVSZ + e];
    }
}

// ---------------- V transpose: Vb[h][s][d] -> Vt[h][d][s] -------------------
__global__ __launch_bounds__(256)
void vtrans(const u16* __restrict__ Vb, u16* __restrict__ Vt) {
    const int s0 = blockIdx.x * 64, d0 = blockIdx.y * 64, h = blockIdx.z;
    __shared__ u16 t[64][72];
    const int tid = threadIdx.x;
    const u16* src = Vb + (size_t)h * S_LEN * HD;
#pragma unroll
    for (int c = tid; c < 512; c += 256) {
        int sr = c >> 3, dc = (c & 7) * 8;
        *(u16x8*)&t[sr][dc] = *(const u16x8*)(src + (size_t)(s0 + sr) * HD + d0 + dc);
    }
    __syncthreads();
    u16* dst = Vt + (size_t)h * HD * S_LEN;
#pragma unroll
    for (int c = tid; c < 512; c += 256) {
        int sc8 = (c & 7) * 8, dd = c >> 3;
        u16x8 v;
#pragma unroll
        for (int j = 0; j < 8; ++j) v[j] = t[sc8 + j][dd];
        *(u16x8*)(dst + (size_t)(d0 + dd) * S_LEN + s0 + sc8) = v;
    }
}

// ---------------- fused sliding-window softcap attention --------------------
// 1D grid of 512; bid&7 = kv head -> XCD-local K/V (4.2 MB fits one L2).
// block = (head, 128 q-rows); 4 waves x 32 q-rows; 32-key tiles.
// K and V staged global->reg (prefetched one tile ahead) -> LDS: no vmem
// drain at barriers, prefetch latency hidden under current tile's compute.
__global__ __launch_bounds__(256, 2)
void attn_fused(const u16* __restrict__ Qb, const u16* __restrict__ Kb,
                const u16* __restrict__ Vt, u16* __restrict__ O) {
    const int bid = blockIdx.x;
    const int hkv = bid & 7;
    const int rest = bid >> 3;            // 0..63
    const int h = hkv * 2 + (rest & 1);
    const int qt = rest >> 1;             // 0..31
    const int qbase = qt * 128;
    const int tid = threadIdx.x, wave = tid >> 6, lane = tid & 63;
    const int quad = lane >> 4, l16 = lane & 15;

    __shared__ u16 lK[32 * 264];          // [key][d], padded rows
    __shared__ u16 lV[256 * 40];          // [d][key], padded (2-way banks)
    __shared__ u16 lP[4][2][16 * 40];     // per-wave P relayout scratch

    const int wlo = qbase + wave * 32;
    const int whi = wlo + 31;

    bf16x8 qf[2][8];
#pragma unroll
    for (int rt = 0; rt < 2; ++rt) {
        const u16* qp = Qb + ((size_t)h * S_LEN + wlo + rt * 16 + l16) * HD + quad * 8;
#pragma unroll
        for (int f = 0; f < 8; ++f) qf[rt][f] = *(const bf16x8*)(qp + f * 32);
    }

    f32x4 zero = {0.f, 0.f, 0.f, 0.f};
    f32x4 o[2][16];
#pragma unroll
    for (int rt = 0; rt < 2; ++rt)
#pragma unroll
        for (int dt = 0; dt < 16; ++dt) o[rt][dt] = zero;
    float l_r[2][4];
#pragma unroll
    for (int rt = 0; rt < 2; ++rt)
#pragma unroll
        for (int r = 0; r < 4; ++r) l_r[rt][r] = 0.f;

    const int t0 = max(0, qbase - WINDOW) >> 5;
    const int t1 = (qbase + 127) >> 5;
    const u16* Kh = Kb + (size_t)hkv * S_LEN * HD;
    const u16* Vh = Vt + (size_t)hkv * HD * S_LEN;

    // K staging: chunk c = tid + it*256: row=c>>5, col=(c&31)*8
    const u16* kbase[4]; int lkoff[4];
    // V staging: chunk c = tid + it*256: d=c>>2, col=(c&3)*8
    const u16* vbase[4]; int lvoff[4];
#pragma unroll
    for (int it = 0; it < 4; ++it) {
        int c = tid + it * 256;
        kbase[it] = Kh + (size_t)(c >> 5) * HD + (c & 31) * 8;
        lkoff[it] = (c >> 5) * 264 + (c & 31) * 8;
        vbase[it] = Vh + (size_t)(c >> 2) * S_LEN + (c & 3) * 8;
        lvoff[it] = (c >> 2) * 40 + (c & 3) * 8;
    }

    // prologue: load first tile into regs
    u16x8 kreg[4], vreg[4];
    const int kb0 = t0 * 32;
#pragma unroll
    for (int it = 0; it < 4; ++it) {
        kreg[it] = *(const u16x8*)(kbase[it] + (size_t)kb0 * HD);
        vreg[it] = *(const u16x8*)(vbase[it] + kb0);
    }

    for (int kt = t0; kt <= t1; ++kt) {
        const int kb = kt * 32;
        __syncthreads();                       // prev tile fully consumed
#pragma unroll
        for (int it = 0; it < 4; ++it) {
            *(u16x8*)(&lK[lkoff[it]]) = kreg[it];
            *(u16x8*)(&lV[lvoff[it]]) = vreg[it];
        }
        __syncthreads();                       // tile visible
        if (kt < t1) {                         // prefetch next (private regs:
#pragma unroll                                 //  no barrier drain needed)
            for (int it = 0; it < 4; ++it) {
                kreg[it] = *(const u16x8*)(kbase[it] + (size_t)(kb + 32) * HD);
                vreg[it] = *(const u16x8*)(vbase[it] + kb + 32);
            }
        }
        bool active = (kb <= whi) && (kb + 31 >= wlo - WINDOW);
        if (!active) continue;

        // QK^T: K-frags shared across the 2 row-tiles
        f32x4 sc[2][2];
        sc[0][0] = zero; sc[0][1] = zero; sc[1][0] = zero; sc[1][1] = zero;
#pragma unroll
        for (int ct = 0; ct < 2; ++ct)
#pragma unroll
            for (int f = 0; f < 8; ++f) {
                bf16x8 kf = *(const bf16x8*)(&lK[(ct * 16 + l16) * 264 + f * 32 + quad * 8]);
                sc[0][ct] = __builtin_amdgcn_mfma_f32_16x16x32_bf16(qf[0][f], kf, sc[0][ct], 0, 0, 0);
                sc[1][ct] = __builtin_amdgcn_mfma_f32_16x16x32_bf16(qf[1][f], kf, sc[1][ct], 0, 0, 0);
            }

        // softcap + mask + fixed-max exp: p = exp(50*tanh(s/50) - 50)
        //                                   = exp(-100/(e^{s/25}+1))
        u16* pw0 = &lP[wave][0][0];
        u16* pw1 = &lP[wave][1][0];
#pragma unroll
        for (int rt = 0; rt < 2; ++rt) {
            u16* pw = rt ? pw1 : pw0;
#pragma unroll
            for (int r = 0; r < 4; ++r) {
                const int gi = wlo + rt * 16 + quad * 4 + r;
#pragma unroll
                for (int ct = 0; ct < 2; ++ct) {
                    const int gj = kb + ct * 16 + l16;
                    float s = sc[rt][ct][r];
                    float u = __expf(s * 0.04f);
                    float p = __expf(-100.f / (u + 1.f));
                    bool ok = (gj <= gi) && (gi - gj <= WINDOW);
                    p = ok ? p : 0.f;
                    l_r[rt][r] += p;
                    pw[(quad * 4 + r) * 40 + ct * 16 + l16] = f2bf(p);
                }
            }
        }
        // C-layout -> A-layout via per-wave LDS round-trip (same-wave ordering)
        asm volatile("s_waitcnt lgkmcnt(0)" ::: "memory");
        bf16x8 pf0 = *(const bf16x8*)(&pw0[l16 * 40 + quad * 8]);
        bf16x8 pf1 = *(const bf16x8*)(&pw1[l16 * 40 + quad * 8]);
#pragma unroll
        for (int dt = 0; dt < 16; ++dt) {
            bf16x8 vf = *(const bf16x8*)(&lV[(dt * 16 + l16) * 40 + quad * 8]);
            o[0][dt] = __builtin_amdgcn_mfma_f32_16x16x32_bf16(pf0, vf, o[0][dt], 0, 0, 0);
            o[1][dt] = __builtin_amdgcn_mfma_f32_16x16x32_bf16(pf1, vf, o[1][dt], 0, 0, 0);
        }
    }

    float inv_l[2][4];
#pragma unroll
    for (int rt = 0; rt < 2; ++rt)
#pragma unroll
        for (int r = 0; r < 4; ++r) {
            float v = l_r[rt][r];
            v += __shfl_xor(v, 1, 64);
            v += __shfl_xor(v, 2, 64);
            v += __shfl_xor(v, 4, 64);
            v += __shfl_xor(v, 8, 64);
            inv_l[rt][r] = 1.f / v;
        }
#pragma unroll
    for (int rt = 0; rt < 2; ++rt)
#pragma unroll
        for (int dt = 0; dt < 16; ++dt)
#pragma unroll
            for (int r = 0; r < 4; ++r) {
                int grow = wlo + rt * 16 + quad * 4 + r;
                int gcol = h * HD + dt * 16 + l16;
                O[(size_t)grow * QSZ + gcol] = f2bf(o[rt][dt][r] * inv_l[rt][r]);
            }
}

// ---------------- launch ----------------------------------------------------
extern "C" void kernel_launch(void* const* d_in, const int* in_sizes, int n_in,
                              void* d_out, int out_size, void* d_ws, size_t ws_size,
                              hipStream_t stream) {
    const float* hidden = (const float*)d_in[1];
    const float* w_qkv  = (const float*)d_in[2];
    const float* w_o    = (const float*)d_in[3];
    float* out = (float*)d_out;

    char* ws = (char*)d_ws;
    size_t off = 0;
    auto alloc = [&](size_t bytes) {
        void* p = ws + off; off += (bytes + 255) & ~(size_t)255; return p;
    };
    u16* Xb    = (u16*)alloc((size_t)S_LEN * HID   * 2);
    u16* Wqkvb = (u16*)alloc((size_t)QKV_N * HID   * 2);
    u16* QKVb  = (u16*)alloc((size_t)S_LEN * QKV_N * 2);
    u16* Qb    = (u16*)alloc((size_t)NH  * S_LEN * HD * 2);
    u16* Kb    = (u16*)alloc((size_t)NKV * S_LEN * HD * 2);
    u16* Vb    = (u16*)alloc((size_t)NKV * S_LEN * HD * 2);
    u16* Vt    = Wqkvb;  // dead after gemm1
    u16* attn  = QKVb;   // dead after rope_split
    u16* Wob   = Xb;     // dead after gemm1

    const int n1 = S_LEN * HID / 4;
    const int n2 = QKV_N * HID / 4;

    cast_f32_bf16<<<dim3((n1 + 255) / 256), dim3(256), 0, stream>>>(hidden, Xb, n1);
    cast_f32_bf16<<<dim3((n2 + 255) / 256), dim3(256), 0, stream>>>(w_qkv, Wqkvb, n2);
    gemm_bt<1><<<dim3(QKV_N / 128, S_LEN / 128), dim3(256), 0, stream>>>(
        Xb, Wqkvb, (void*)QKVb, S_LEN, QKV_N, HID);
    rope_split<<<dim3(S_LEN), dim3(256), 0, stream>>>(QKVb, Qb, Kb, Vb);
    vtrans<<<dim3(S_LEN / 64, HD / 64, NKV), dim3(256), 0, stream>>>(Vb, Vt);
    cast_f32_bf16<<<dim3((n1 + 255) / 256), dim3(256), 0, stream>>>(w_o, Wob, n1);
    attn_fused<<<dim3(512), dim3(256), 0, stream>>>(Qb, Kb, Vt, attn);
    gemm_bt<0><<<dim3(HID / 128, S_LEN / 128), dim3(256), 0, stream>>>(
        attn, Wob, (void*)out, S_LEN, HID, QSZ);
}

// Round 4
// 1185.070 us; speedup vs baseline: 1.1961x; 1.1961x over previous
//
#include <hip/hip_runtime.h>
#include <cstdint>
#include <cstddef>

#define S_LEN 4096
#define HID   3584
#define NH    16
#define NKV   8
#define HD    256
#define QSZ   (NH*HD)            // 4096
#define KVSZ  (NKV*HD)           // 2048
#define QKV_N (QSZ + 2*KVSZ)     // 8192
#define WINDOW 2047

typedef unsigned short u16;
typedef __bf16 bf16x8 __attribute__((ext_vector_type(8)));
typedef u16    u16x8  __attribute__((ext_vector_type(8)));
typedef u16    u16x4  __attribute__((ext_vector_type(4)));
typedef float  f32x4  __attribute__((ext_vector_type(4)));

__device__ inline float bf2f(u16 u) {
    union { unsigned u; float f; } v; v.u = ((unsigned)u) << 16; return v.f;
}
__device__ inline u16 f2bf(float f) {
    union { float f; unsigned u; } v; v.f = f;
    return (u16)((v.u + 0x7FFF + ((v.u >> 16) & 1)) >> 16);
}

// async global->LDS DMA, 16B per lane; LDS dest = wave-uniform base + lane*16
__device__ inline void gl_lds16(const void* g, void* l) {
    __builtin_amdgcn_global_load_lds(
        (const __attribute__((address_space(1))) void*)g,
        (__attribute__((address_space(3))) void*)l,
        16, 0, 0);
}

// ---------------- fp32 -> bf16 cast (vectorized) ----------------
__global__ __launch_bounds__(256)
void cast_f32_bf16(const float* __restrict__ src, u16* __restrict__ dst, int n4) {
    int i = blockIdx.x * blockDim.x + threadIdx.x;
    if (i >= n4) return;
    float4 v = ((const float4*)src)[i];
    u16x4 o;
    o[0] = f2bf(v.x); o[1] = f2bf(v.y); o[2] = f2bf(v.z); o[3] = f2bf(v.w);
    ((u16x4*)dst)[i] = o;
}

// ---------------- bf16 GEMM, C[m,n] = sum_k A[m,k]*B[n,k] (both K-major) ----
// 128x128 tile, BK=32, 4 waves 2x2, global_load_lds width-16 staging (m97).
template<int BF16OUT>
__global__ __launch_bounds__(256)
void gemm_bt(const u16* __restrict__ A, const u16* __restrict__ B,
             void* __restrict__ Cv, int M, int N, int K) {
    __shared__ u16 lA[128 * 32];
    __shared__ u16 lB[128 * 32];
    const int tid  = threadIdx.x;
    const int lane = tid & 63, wave = tid >> 6;
    const int quad = lane >> 4, l16 = lane & 15;
    const int m0 = blockIdx.y * 128, n0 = blockIdx.x * 128;
    const int wm = (wave & 1) * 64, wn = (wave >> 1) * 64;

    const int c0 = wave * 128 + lane, c1 = c0 + 64;
    const u16* gA0 = A + (size_t)(m0 + (c0 >> 2)) * K + (c0 & 3) * 8;
    const u16* gA1 = A + (size_t)(m0 + (c1 >> 2)) * K + (c1 & 3) * 8;
    const u16* gB0 = B + (size_t)(n0 + (c0 >> 2)) * K + (c0 & 3) * 8;
    const u16* gB1 = B + (size_t)(n0 + (c1 >> 2)) * K + (c1 & 3) * 8;
    char* lA0 = (char*)lA + wave * 2048;
    char* lB0 = (char*)lB + wave * 2048;

    f32x4 zero = {0.f, 0.f, 0.f, 0.f};
    f32x4 acc[4][4];
#pragma unroll
    for (int i = 0; i < 4; ++i)
#pragma unroll
        for (int j = 0; j < 4; ++j) acc[i][j] = zero;

    for (int k0 = 0; k0 < K; k0 += 32) {
        __syncthreads();
        gl_lds16(gA0 + k0, lA0);
        gl_lds16(gA1 + k0, lA0 + 1024);
        gl_lds16(gB0 + k0, lB0);
        gl_lds16(gB1 + k0, lB0 + 1024);
        __syncthreads();

        bf16x8 af[4], bfr[4];
#pragma unroll
        for (int mt = 0; mt < 4; ++mt)
            af[mt] = *(const bf16x8*)(&lA[(wm + mt * 16 + l16) * 32 + quad * 8]);
#pragma unroll
        for (int nt = 0; nt < 4; ++nt)
            bfr[nt] = *(const bf16x8*)(&lB[(wn + nt * 16 + l16) * 32 + quad * 8]);
#pragma unroll
        for (int mt = 0; mt < 4; ++mt)
#pragma unroll
            for (int nt = 0; nt < 4; ++nt)
                acc[mt][nt] = __builtin_amdgcn_mfma_f32_16x16x32_bf16(
                    af[mt], bfr[nt], acc[mt][nt], 0, 0, 0);
    }

#pragma unroll
    for (int mt = 0; mt < 4; ++mt)
#pragma unroll
        for (int nt = 0; nt < 4; ++nt)
#pragma unroll
            for (int r = 0; r < 4; ++r) {
                int row = m0 + wm + mt * 16 + quad * 4 + r;
                int col = n0 + wn + nt * 16 + l16;
                float v = acc[mt][nt][r];
                if (BF16OUT) ((u16*)Cv)[(size_t)row * N + col] = f2bf(v);
                else         ((float*)Cv)[(size_t)row * N + col] = v;
            }
}

// ---------------- RoPE (NeoX) + split + per-head relayout -------------------
__global__ __launch_bounds__(256)
void rope_split(const u16* __restrict__ qkv, u16* __restrict__ Qb,
                u16* __restrict__ Kb, u16* __restrict__ Vb) {
    const int s = blockIdx.x;
    const int t = threadIdx.x;
    const float pos = (float)s;
    const u16* row = qkv + (size_t)s * QKV_N;

    for (int p = t; p < 2048; p += 256) {      // Q: 16 heads x 128 pairs
        int h = p >> 7, d = p & 127;
        float inv = __expf(-(float)d * 0.0719557841560639f);  // ln(1e4)/128
        float ang = pos * inv, sn, cs;
        sincosf(ang, &sn, &cs);
        float x1 = bf2f(row[h * HD + d]);
        float x2 = bf2f(row[h * HD + d + 128]);
        size_t base = ((size_t)h * S_LEN + s) * HD;
        Qb[base + d]       = f2bf((x1 * cs - x2 * sn) * 0.0625f);  // fold 1/16 scale
        Qb[base + d + 128] = f2bf((x2 * cs + x1 * sn) * 0.0625f);
    }
    for (int p = t; p < 1024; p += 256) {      // K: 8 heads x 128 pairs
        int h = p >> 7, d = p & 127;
        float inv = __expf(-(float)d * 0.0719557841560639f);
        float ang = pos * inv, sn, cs;
        sincosf(ang, &sn, &cs);
        float x1 = bf2f(row[QSZ + h * HD + d]);
        float x2 = bf2f(row[QSZ + h * HD + d + 128]);
        size_t base = ((size_t)h * S_LEN + s) * HD;
        Kb[base + d]       = f2bf(x1 * cs - x2 * sn);
        Kb[base + d + 128] = f2bf(x2 * cs + x1 * sn);
    }
    for (int e = t; e < 2048; e += 256) {      // V: natural [h][s][d]
        int h = e >> 8, d = e & 255;
        Vb[((size_t)h * S_LEN + s) * HD + d] = row[QSZ + KVSZ + e];
    }
}

// ---------------- V transpose: Vb[h][s][d] -> Vt[h][d][s] -------------------
__global__ __launch_bounds__(256)
void vtrans(const u16* __restrict__ Vb, u16* __restrict__ Vt) {
    const int s0 = blockIdx.x * 64, d0 = blockIdx.y * 64, h = blockIdx.z;
    __shared__ u16 t[64][72];
    const int tid = threadIdx.x;
    const u16* src = Vb + (size_t)h * S_LEN * HD;
#pragma unroll
    for (int c = tid; c < 512; c += 256) {
        int sr = c >> 3, dc = (c & 7) * 8;
        *(u16x8*)&t[sr][dc] = *(const u16x8*)(src + (size_t)(s0 + sr) * HD + d0 + dc);
    }
    __syncthreads();
    u16* dst = Vt + (size_t)h * HD * S_LEN;
#pragma unroll
    for (int c = tid; c < 512; c += 256) {
        int sc8 = (c & 7) * 8, dd = c >> 3;
        u16x8 v;
#pragma unroll
        for (int j = 0; j < 8; ++j) v[j] = t[sc8 + j][dd];
        *(u16x8*)(dst + (size_t)(d0 + dd) * S_LEN + s0 + sc8) = v;
    }
}

// ---------------- fused sliding-window softcap attention --------------------
// Grid 1024, bid&7 = kv head (XCD-local K/V ~4.2 MB -> one L2).
// block = 64 q-rows of one head; 4 waves x 16 q-rows; 32-key tiles.
// Fixed-max softmax (scores capped at 50 => m:=50): p = exp(-100/(e^{s/25}+1)).
// K/V prefetched global->reg one tile ahead, reg->LDS at barrier (no vmem
// drain at barriers). Register budget: o[16]=64 + qf[8]=32 + kreg/vreg=32
// ~ 128+temps; launch_bounds(256,3) caps at ~170 -> NO SPILLS (round-3 bug).
__global__ __launch_bounds__(256, 3)
void attn_fused(const u16* __restrict__ Qb, const u16* __restrict__ Kb,
                const u16* __restrict__ Vt, u16* __restrict__ O) {
    const int bid = blockIdx.x;
    const int hkv = bid & 7;
    const int rest = bid >> 3;            // 0..127
    const int h = hkv * 2 + (rest & 1);
    const int qt = rest >> 1;             // 0..63
    const int qbase = qt * 64;
    const int tid = threadIdx.x, wave = tid >> 6, lane = tid & 63;
    const int quad = lane >> 4, l16 = lane & 15;

    __shared__ u16 lK[32 * 264];          // [key][d], padded rows
    __shared__ u16 lV[256 * 40];          // [d][key], padded (balanced banks)
    __shared__ u16 lP[4][16 * 40];        // per-wave P relayout scratch

    const int wlo = qbase + wave * 16;    // wave's q-rows: wlo..wlo+15
    const int whi = wlo + 15;

    bf16x8 qf[8];
    {
        const u16* qp = Qb + ((size_t)h * S_LEN + wlo + l16) * HD + quad * 8;
#pragma unroll
        for (int f = 0; f < 8; ++f) qf[f] = *(const bf16x8*)(qp + f * 32);
    }

    f32x4 zero = {0.f, 0.f, 0.f, 0.f};
    f32x4 o[16];
#pragma unroll
    for (int dt = 0; dt < 16; ++dt) o[dt] = zero;
    float l_r[4];
#pragma unroll
    for (int r = 0; r < 4; ++r) l_r[r] = 0.f;

    const int t0 = max(0, qbase - WINDOW) >> 5;
    const int t1 = (qbase + 63) >> 5;
    const u16* Kh = Kb + (size_t)hkv * S_LEN * HD;
    const u16* Vh = Vt + (size_t)hkv * HD * S_LEN;

    // K staging: chunk c = tid + it*256: row=c>>5, col=(c&31)*8
    // V staging: chunk c = tid + it*256: d=c>>2, col=(c&3)*8
    const u16* kbase[4]; int lkoff[4];
    const u16* vbase[4]; int lvoff[4];
#pragma unroll
    for (int it = 0; it < 4; ++it) {
        int c = tid + it * 256;
        kbase[it] = Kh + (size_t)(c >> 5) * HD + (c & 31) * 8;
        lkoff[it] = (c >> 5) * 264 + (c & 31) * 8;
        vbase[it] = Vh + (size_t)(c >> 2) * S_LEN + (c & 3) * 8;
        lvoff[it] = (c >> 2) * 40 + (c & 3) * 8;
    }

    // prologue: first tile into regs
    u16x8 kreg[4], vreg[4];
    const int kb0 = t0 * 32;
#pragma unroll
    for (int it = 0; it < 4; ++it) {
        kreg[it] = *(const u16x8*)(kbase[it] + (size_t)kb0 * HD);
        vreg[it] = *(const u16x8*)(vbase[it] + kb0);
    }

    for (int kt = t0; kt <= t1; ++kt) {
        const int kb = kt * 32;
        __syncthreads();                       // prev tile fully consumed
#pragma unroll
        for (int it = 0; it < 4; ++it) {
            *(u16x8*)(&lK[lkoff[it]]) = kreg[it];
            *(u16x8*)(&lV[lvoff[it]]) = vreg[it];
        }
        __syncthreads();                       // tile visible
        if (kt < t1) {                         // prefetch next into private regs
#pragma unroll
            for (int it = 0; it < 4; ++it) {
                kreg[it] = *(const u16x8*)(kbase[it] + (size_t)(kb + 32) * HD);
                vreg[it] = *(const u16x8*)(vbase[it] + kb + 32);
            }
        }
        bool active = (kb <= whi) && (kb + 31 >= wlo - WINDOW);
        if (!active) continue;

        // QK^T
        f32x4 sc[2];
        sc[0] = zero; sc[1] = zero;
#pragma unroll
        for (int ct = 0; ct < 2; ++ct)
#pragma unroll
            for (int f = 0; f < 8; ++f) {
                bf16x8 kf = *(const bf16x8*)(&lK[(ct * 16 + l16) * 264 + f * 32 + quad * 8]);
                sc[ct] = __builtin_amdgcn_mfma_f32_16x16x32_bf16(qf[f], kf, sc[ct], 0, 0, 0);
            }

        // softcap + mask + fixed-max exp: p = exp(50*tanh(s/50) - 50)
        //                                   = exp(-100/(e^{s/25}+1))
        u16* pw = &lP[wave][0];
#pragma unroll
        for (int r = 0; r < 4; ++r) {
            const int gi = wlo + quad * 4 + r;
#pragma unroll
            for (int ct = 0; ct < 2; ++ct) {
                const int gj = kb + ct * 16 + l16;
                float s = sc[ct][r];
                float u = __expf(s * 0.04f);
                float p = __expf(-100.f / (u + 1.f));
                bool ok = (gj <= gi) && (gi - gj <= WINDOW);
                p = ok ? p : 0.f;
                l_r[r] += p;
                pw[(quad * 4 + r) * 40 + ct * 16 + l16] = f2bf(p);
            }
        }
        // C-layout -> A-layout via per-wave LDS round-trip (same-wave ordering)
        asm volatile("s_waitcnt lgkmcnt(0)" ::: "memory");
        bf16x8 pf = *(const bf16x8*)(&pw[l16 * 40 + quad * 8]);
#pragma unroll
        for (int dt = 0; dt < 16; ++dt) {
            bf16x8 vf = *(const bf16x8*)(&lV[(dt * 16 + l16) * 40 + quad * 8]);
            o[dt] = __builtin_amdgcn_mfma_f32_16x16x32_bf16(pf, vf, o[dt], 0, 0, 0);
        }
    }

    float inv_l[4];
#pragma unroll
    for (int r = 0; r < 4; ++r) {
        float v = l_r[r];
        v += __shfl_xor(v, 1, 64);
        v += __shfl_xor(v, 2, 64);
        v += __shfl_xor(v, 4, 64);
        v += __shfl_xor(v, 8, 64);
        inv_l[r] = 1.f / v;
    }
#pragma unroll
    for (int dt = 0; dt < 16; ++dt)
#pragma unroll
        for (int r = 0; r < 4; ++r) {
            int grow = wlo + quad * 4 + r;
            int gcol = h * HD + dt * 16 + l16;
            O[(size_t)grow * QSZ + gcol] = f2bf(o[dt][r] * inv_l[r]);
        }
}

// ---------------- launch ----------------------------------------------------
extern "C" void kernel_launch(void* const* d_in, const int* in_sizes, int n_in,
                              void* d_out, int out_size, void* d_ws, size_t ws_size,
                              hipStream_t stream) {
    const float* hidden = (const float*)d_in[1];
    const float* w_qkv  = (const float*)d_in[2];
    const float* w_o    = (const float*)d_in[3];
    float* out = (float*)d_out;

    char* ws = (char*)d_ws;
    size_t off = 0;
    auto alloc = [&](size_t bytes) {
        void* p = ws + off; off += (bytes + 255) & ~(size_t)255; return p;
    };
    u16* Xb    = (u16*)alloc((size_t)S_LEN * HID   * 2);
    u16* Wqkvb = (u16*)alloc((size_t)QKV_N * HID   * 2);
    u16* QKVb  = (u16*)alloc((size_t)S_LEN * QKV_N * 2);
    u16* Qb    = (u16*)alloc((size_t)NH  * S_LEN * HD * 2);
    u16* Kb    = (u16*)alloc((size_t)NKV * S_LEN * HD * 2);
    u16* Vb    = (u16*)alloc((size_t)NKV * S_LEN * HD * 2);
    u16* Vt    = Wqkvb;  // dead after gemm1
    u16* attn  = QKVb;   // dead after rope_split
    u16* Wob   = Xb;     // dead after gemm1

    const int n1 = S_LEN * HID / 4;
    const int n2 = QKV_N * HID / 4;

    cast_f32_bf16<<<dim3((n1 + 255) / 256), dim3(256), 0, stream>>>(hidden, Xb, n1);
    cast_f32_bf16<<<dim3((n2 + 255) / 256), dim3(256), 0, stream>>>(w_qkv, Wqkvb, n2);
    gemm_bt<1><<<dim3(QKV_N / 128, S_LEN / 128), dim3(256), 0, stream>>>(
        Xb, Wqkvb, (void*)QKVb, S_LEN, QKV_N, HID);
    rope_split<<<dim3(S_LEN), dim3(256), 0, stream>>>(QKVb, Qb, Kb, Vb);
    vtrans<<<dim3(S_LEN / 64, HD / 64, NKV), dim3(256), 0, stream>>>(Vb, Vt);
    cast_f32_bf16<<<dim3((n1 + 255) / 256), dim3(256), 0, stream>>>(w_o, Wob, n1);
    attn_fused<<<dim3(1024), dim3(256), 0, stream>>>(Qb, Kb, Vt, attn);
    gemm_bt<0><<<dim3(HID / 128, S_LEN / 128), dim3(256), 0, stream>>>(
        attn, Wob, (void*)out, S_LEN, HID, QSZ);
}